// Round 9
// baseline (671.827 us; speedup 1.0000x reference)
//
#include <hip/hip_runtime.h>
#include <hip/hip_bf16.h>
#include <cmath>

// Problem constants
#define BB 64
#define TT 2048
#define EE 1024
#define DD 1024
#define FAN 2048

typedef __attribute__((ext_vector_type(8))) short bhalf8;
typedef __attribute__((ext_vector_type(4))) float fvec4;

// ws layout (bytes) — high water 6.75 MB (< 7.6 MB proven available)
#define OFF_WE   0u          // 2 MB  : We bf16, pre-swizzled [ec][eo][d][8]
#define OFF_C    2097152u    // 256 KB: c[b,d] = dec·Wd + bias
#define OFF_SP   2359296u    // 2 MB  : score partials [4 dq][64 b][2048 t]
#define OFF_A    4456448u    // 512 KB: alpha[b,t]
#define OFF_P    4980736u    // 2 MB  : context partials [8 ts][64 b][1024 e]

__device__ __forceinline__ short f2bf(float f) {
    unsigned int u = __float_as_uint(f);
    u += 0x7FFFu + ((u >> 16) & 1u);   // round-to-nearest-even
    return (short)(u >> 16);
}

__device__ __forceinline__ bhalf8 cvt8(float4 a, float4 b) {
    bhalf8 h;
    h[0] = f2bf(a.x); h[1] = f2bf(a.y); h[2] = f2bf(a.z); h[3] = f2bf(a.w);
    h[4] = f2bf(b.x); h[5] = f2bf(b.y); h[6] = f2bf(b.z); h[7] = f2bf(b.w);
    return h;
}

__device__ __forceinline__ float fast_tanhf(float x) {
    float ax = __builtin_fabsf(x);
    float e  = __expf(-2.0f * ax);
    float r  = (1.0f - e) * __builtin_amdgcn_rcpf(1.0f + e);
    return __builtin_copysignf(r, x);
}

// ---------------- kernel 0a: convert We (f32) -> pre-swizzled bf16 image ----
// image layout per 32-wide e-chunk ec: byte = ec*65536 + eo*16384 + d*16 + r*2
__global__ void prep_we_k(const float* __restrict__ W, short* __restrict__ wsWe) {
    int g  = blockIdx.x * 256 + threadIdx.x;   // 0..131071
    int ec = g >> 12;          // 0..31
    int eo = (g >> 10) & 3;    // 0..3
    int d  = g & 1023;
    const float* src = W + (size_t)d * FAN + ec * 32 + eo * 8;
    float4 f0 = *(const float4*)src;
    float4 f1 = *(const float4*)(src + 4);
    *(bhalf8*)((char*)wsWe + (size_t)ec * 65536 + eo * 16384 + d * 16) = cvt8(f0, f1);
}

// ---------------- kernel 0b: c[b,d] = dec[b,:]·Wd[d,:] + bias[d] ------------
__global__ void prep_c_k(const float* __restrict__ W, const float* __restrict__ bias,
                         const float* __restrict__ dec, float* __restrict__ cbuf) {
    int wg   = blockIdx.x * 4 + (threadIdx.x >> 6);  // 0..65535
    int lane = threadIdx.x & 63;
    int b = wg >> 10, d = wg & 1023;
    const float* wrow = W + (size_t)d * FAN + EE;    // Wd part
    const float* drow = dec + b * DD;
    float p = 0.f;
#pragma unroll
    for (int i = 0; i < 16; ++i)
        p += wrow[i * 64 + lane] * drow[i * 64 + lane];
#pragma unroll
    for (int off = 1; off < 64; off <<= 1)
        p += __shfl_xor(p, off);
    if (lane == 0) cbuf[b * DD + d] = p + bias[d];
}

// ---------------- kernel 1: partial scores, M=256 t x N=256 d per block -----
// grid (8 t-tiles x 4 d-quarters, 64 b), 512 thr (8 waves, 4m x 2n),
// wave-tile 64t x 128d (acc=128). The 4 m-waves issue IDENTICAL B loads ->
// L1 dedup (16 KB/ks slab fits L1): per-block cross-L2 traffic ~1.5 MB vs
// 2.25 MB at M=64; total B L2-traffic 4 GB -> 1 GB. K-loop body = round-4
// proven pattern: depth-1 register prefetch of fp32 A, cvt + XOR-swizzled
// ds_write (0 conflicts), BK=64, one __syncthreads per step. Epilogue:
// partial v-dot over this block's 256 d's -> sp[dq][b][t] (deterministic,
// no atomics).
__global__ __launch_bounds__(512, 2)
void scores_k(const float* __restrict__ enc, const short* __restrict__ wsWe,
              const float* __restrict__ cbuf, const float* __restrict__ vw,
              float* __restrict__ sp) {
    __shared__ short sA[2][8][256][8];  // 64 KB: [buf][eo][t^eo][8e]
    __shared__ float sRed[8][64];       // 2 KB

    const int tid  = threadIdx.x;
    const int w    = tid >> 6;
    const int wm   = w >> 1;      // 0..3 (t sub-tile)
    const int wn   = w & 1;       // 0..1 (d sub-tile)
    const int lane = tid & 63;
    const int lrow = lane >> 4;   // 0..3
    const int lcol = lane & 15;
    const int b  = blockIdx.y;
    const int tt = blockIdx.x >> 2;       // t-tile 0..7
    const int dq = blockIdx.x & 3;        // d-quarter 0..3
    const int t0 = tt * 256;

    // staging: thread -> 4 rows (st + 64q), e-octet seo; coalesced 256B runs
    const int st  = tid >> 3;     // 0..63
    const int seo = tid & 7;      // 0..7
    const float* gsrc = enc + ((size_t)(b * TT + t0 + st)) * EE + seo * 8;

    fvec4 acc[4][8];
#pragma unroll
    for (int m = 0; m < 4; ++m)
#pragma unroll
        for (int n = 0; n < 8; ++n)
            acc[m][n] = (fvec4){0.f, 0.f, 0.f, 0.f};

    // per-lane B base in the image: eo=lrow, d = dq*256 + wn*128 + lcol
    const char* Bbase = (const char*)wsWe + lrow * 16384
                      + (size_t)(dq * 256 + wn * 128 + lcol) * 16;

    // ---- prologue: stage chunk 0
    {
        float4 x0, x1;
#pragma unroll
        for (int q = 0; q < 4; ++q) {
            const float* s = gsrc + (size_t)q * 64 * EE;
            x0 = *(const float4*)s; x1 = *(const float4*)(s + 4);
            int t = st + q * 64;
            *(bhalf8*)&sA[0][seo][t ^ seo][0] = cvt8(x0, x1);
        }
    }
    __syncthreads();

#pragma unroll 2
    for (int i = 0; i < 16; ++i) {
        const int buf = i & 1, nbuf = buf ^ 1;
        // (1) prefetch fp32 A chunk i+1 into registers
        float4 f0[4], f1[4];
        if (i < 15) {
#pragma unroll
            for (int q = 0; q < 4; ++q) {
                const float* s = gsrc + (size_t)q * 64 * EE + (i + 1) * 64;
                f0[q] = *(const float4*)s;
                f1[q] = *(const float4*)(s + 4);
            }
        }
        // (2) compute chunk i: 2 ks halves
#pragma unroll
        for (int kk = 0; kk < 2; ++kk) {
            bhalf8 bf[8];
#pragma unroll
            for (int n = 0; n < 8; ++n)
                bf[n] = *(const bhalf8*)(Bbase + (size_t)(2 * i + kk) * 65536 + n * 256);
            bhalf8 af[4];
#pragma unroll
            for (int m = 0; m < 4; ++m) {
                int t  = wm * 64 + m * 16 + lcol;
                int eo = kk * 4 + lrow;
                af[m] = *(const bhalf8*)&sA[buf][eo][t ^ eo][0];
            }
#pragma unroll
            for (int n = 0; n < 8; ++n)
#pragma unroll
                for (int m = 0; m < 4; ++m)
                    acc[m][n] = __builtin_amdgcn_mfma_f32_16x16x32_bf16(af[m], bf[n], acc[m][n], 0, 0, 0);
        }
        // (3) cvt + swizzled write of chunk i+1
        if (i < 15) {
#pragma unroll
            for (int q = 0; q < 4; ++q) {
                int t = st + q * 64;
                *(bhalf8*)&sA[nbuf][seo][t ^ seo][0] = cvt8(f0[q], f1[q]);
            }
        }
        __syncthreads();
    }

    float cv[8], vv[8];
#pragma unroll
    for (int n = 0; n < 8; ++n) {
        int d = dq * 256 + wn * 128 + n * 16 + lcol;
        cv[n] = cbuf[b * DD + d];
        vv[n] = vw[d];
    }

    // epilogue: tanh + partial v-dot over this wave's 128 d's
#pragma unroll
    for (int m = 0; m < 4; ++m) {
#pragma unroll
        for (int j = 0; j < 4; ++j) {
            float p = 0.f;
#pragma unroll
            for (int n = 0; n < 8; ++n)
                p += vv[n] * fast_tanhf(acc[m][n][j] + cv[n]);
            p += __shfl_xor(p, 1); p += __shfl_xor(p, 2);
            p += __shfl_xor(p, 4); p += __shfl_xor(p, 8);
            if (lcol == 0) sRed[w][m * 16 + lrow * 4 + j] = p;
        }
    }
    __syncthreads();
    if (tid < 256) {
        int r  = tid;              // row within t-tile
        int rm = r >> 6, lr = r & 63;
        float v2 = sRed[2 * rm][lr] + sRed[2 * rm + 1][lr];
        sp[((size_t)dq * BB + b) * TT + t0 + r] = v2;
    }
}

// ---------------- kernel 2: sum partials + softmax over t per batch ---------
__global__ void softmax_k(const float* __restrict__ sp, float* __restrict__ alpha) {
    int b = blockIdx.x, tid = threadIdx.x;
    float s[8];
    float m = -1e30f;
#pragma unroll
    for (int i = 0; i < 8; ++i) {
        size_t idx = (size_t)b * TT + i * 256 + tid;
        s[i] = sp[idx] + sp[(size_t)BB * TT + idx]
             + sp[2 * (size_t)BB * TT + idx] + sp[3 * (size_t)BB * TT + idx];
        m = fmaxf(m, s[i]);
    }
#pragma unroll
    for (int off = 1; off < 64; off <<= 1) m = fmaxf(m, __shfl_xor(m, off));
    __shared__ float red[4], red2[4];
    if ((tid & 63) == 0) red[tid >> 6] = m;
    __syncthreads();
    m = fmaxf(fmaxf(red[0], red[1]), fmaxf(red[2], red[3]));
    float sum = 0.f;
#pragma unroll
    for (int i = 0; i < 8; ++i) { s[i] = expf(s[i] - m); sum += s[i]; }
#pragma unroll
    for (int off = 1; off < 64; off <<= 1) sum += __shfl_xor(sum, off);
    if ((tid & 63) == 0) red2[tid >> 6] = sum;
    __syncthreads();
    sum = red2[0] + red2[1] + red2[2] + red2[3];
    float inv = 1.0f / sum;
#pragma unroll
    for (int i = 0; i < 8; ++i) alpha[b * TT + i * 256 + tid] = s[i] * inv;
}

// ---------------- kernel 3: context partials over t-slices ------------------
// grid (8 t-slices, 64 b), 256 thr, each thread owns 4 consecutive e
__global__ void ctx_k(const float* __restrict__ enc, const float* __restrict__ alpha,
                      float* __restrict__ part) {
    int ts = blockIdx.x, b = blockIdx.y, tid = threadIdx.x;
    __shared__ float sAl[256];
    sAl[tid] = alpha[b * TT + ts * 256 + tid];
    __syncthreads();
    float4 acc = {0.f, 0.f, 0.f, 0.f};
    const float* base = enc + ((size_t)b * TT + ts * 256) * EE + tid * 4;
#pragma unroll 8
    for (int i = 0; i < 256; ++i) {
        float4 v = *(const float4*)(base + (size_t)i * EE);
        float a = sAl[i];
        acc.x += a * v.x; acc.y += a * v.y; acc.z += a * v.z; acc.w += a * v.w;
    }
    *(float4*)&part[(size_t)(ts * 64 + b) * EE + tid * 4] = acc;
}

// ---------------- kernel 4: combine partials --------------------------------
__global__ void comb_k(const float* __restrict__ part, float* __restrict__ out) {
    int g = blockIdx.x * 256 + threadIdx.x;   // 0..65535
    float s = 0.f;
#pragma unroll
    for (int ts = 0; ts < 8; ++ts) s += part[(size_t)ts * 65536 + g];
    out[g] = s;
}

extern "C" void kernel_launch(void* const* d_in, const int* in_sizes, int n_in,
                              void* d_out, int out_size, void* d_ws, size_t ws_size,
                              hipStream_t stream) {
    const float* enc  = (const float*)d_in[0];
    const float* dec  = (const float*)d_in[1];
    const float* W    = (const float*)d_in[2];
    const float* bias = (const float*)d_in[3];
    const float* vw   = (const float*)d_in[4];
    float* out = (float*)d_out;

    char* ws = (char*)d_ws;
    short* wsWe   = (short*)(ws + OFF_WE);
    float* cbuf   = (float*)(ws + OFF_C);
    float* sp     = (float*)(ws + OFF_SP);
    float* alpha  = (float*)(ws + OFF_A);
    float* part   = (float*)(ws + OFF_P);

    prep_we_k<<<512, 256, 0, stream>>>(W, wsWe);
    prep_c_k<<<16384, 256, 0, stream>>>(W, bias, dec, cbuf);
    scores_k<<<dim3(32, 64), 512, 0, stream>>>(enc, wsWe, cbuf, vw, sp);
    softmax_k<<<64, 256, 0, stream>>>(sp, alpha);
    ctx_k<<<dim3(8, 64), 256, 0, stream>>>(enc, alpha, part);
    comb_k<<<256, 256, 0, stream>>>(part, out);
}